// Round 5
// baseline (134.963 us; speedup 1.0000x reference)
//
#include <hip/hip_runtime.h>
#include <hip/hip_cooperative_groups.h>

namespace cg = cooperative_groups;

typedef int iv4 __attribute__((ext_vector_type(4)));

struct W { double shear, scale, bend; };

__device__ __forceinline__ W softw(const float* __restrict__ rw) {
    double r0 = (double)rw[0], r1 = (double)rw[1], r2 = (double)rw[2];
    double mx = fmax(r0, fmax(r1, r2));
    double e0 = exp(r0 - mx), e1 = exp(r1 - mx), e2 = exp(r2 - mx);
    double s = 1.0 / (e0 + e1 + e2);
    W w; w.shear = e0 * s; w.scale = 0.1 * (e1 * s); w.bend = 0.01 * (e2 * s);
    return w;
}

__device__ __forceinline__ float3 ldv(const float* __restrict__ p) {
    return *reinterpret_cast<const float3*>(p);
}

// Per-face loss*area in double.
__device__ __forceinline__ double face_term(
    float3 s0, float3 s1, float3 s2,
    float3 t0, float3 t1, float3 t2,
    double w_shear, double c_scale, double c_bend)
{
    double e1x = (double)s1.x - s0.x, e1y = (double)s1.y - s0.y, e1z = (double)s1.z - s0.z;
    double e2x = (double)s2.x - s0.x, e2y = (double)s2.y - s0.y, e2z = (double)s2.z - s0.z;
    double f1x = e1x - ((double)t1.x - t0.x), f1y = e1y - ((double)t1.y - t0.y), f1z = e1z - ((double)t1.z - t0.z);
    double f2x = e2x - ((double)t2.x - t0.x), f2y = e2y - ((double)t2.y - t0.y), f2z = e2z - ((double)t2.z - t0.z);

    double a = e1x * e1x + e1y * e1y + e1z * e1z;
    double b = e1x * e2x + e1y * e2y + e1z * e2z;
    double c = e2x * e2x + e2y * e2y + e2z * e2z;
    double det = a * c - b * b;

    double crx = e1y * e2z - e1z * e2y;
    double cry = e1z * e2x - e1x * e2z;
    double crz = e1x * e2y - e1y * e2x;
    double crn = crx * crx + cry * cry + crz * crz;
    double area = 0.5 * sqrt(crn);

    double P = crx * f1x + cry * f1y + crz * f1z;
    double Q = crx * f2x + cry * f2y + crz * f2z;
    double norm_loss = (c * P * P - 2.0 * b * P * Q + a * Q * Q) / (det * crn);

    double fe11 = f1x * e1x + f1y * e1y + f1z * e1z;
    double fe12 = f1x * e2x + f1y * e2y + f1z * e2z;
    double fe21 = f2x * e1x + f2y * e1y + f2z * e1z;
    double fe22 = f2x * e2x + f2y * e2y + f2z * e2z;
    double D00 = 2.0 * fe11;
    double D01 = fe12 + fe21;
    double D11 = 2.0 * fe22;

    double idet = 1.0 / det;
    double inv00 = c * idet, inv01 = -b * idet, inv11 = a * idet;

    double stretch = inv00 * D00 + 2.0 * inv01 * D01 + inv11 * D11;
    double offdiag = inv00 * D01 + inv01 * D11 + inv01 * D00 + inv11 * D01;

    double loss = c_bend * norm_loss + c_scale * stretch + w_shear * offdiag;
    return loss * area;
}

__device__ __forceinline__ double quad_sum(iv4 A, iv4 B, iv4 C,
    const float* __restrict__ vs, const float* __restrict__ vt,
    const W& w, const float* __restrict__ term)
{
    int i0[4] = { A[0], A[3], B[2], C[1] };
    int i1[4] = { A[1], B[0], B[3], C[2] };
    int i2[4] = { A[2], B[1], C[0], C[3] };
    double a = 0.0;
    #pragma unroll
    for (int k = 0; k < 4; ++k) {
        if (__builtin_expect(i1[k] == i0[k] + 1 && i2[k] == i0[k] + 2, 1)) {
            a += (double)term[i0[k]];
        } else {   // never taken for this dataset; correctness insurance
            a += face_term(ldv(vs + 3 * i0[k]), ldv(vs + 3 * i1[k]), ldv(vs + 3 * i2[k]),
                           ldv(vt + 3 * i0[k]), ldv(vt + 3 * i1[k]), ldv(vt + 3 * i2[k]),
                           w.shear, w.scale, w.bend);
        }
    }
    return a;
}

__device__ __forceinline__ double block_reduce(double a, double* sm) {
    for (int off = 32; off > 0; off >>= 1)
        a += __shfl_down(a, off);
    int lane = threadIdx.x & 63;
    int wid = threadIdx.x >> 6;
    if (lane == 0) sm[wid] = a;
    __syncthreads();
    return sm[0] + sm[1] + sm[2] + sm[3];
}

// ---------- fused cooperative kernel (1 launch, 2 grid syncs) ----------
__global__ void __launch_bounds__(256, 2) deform_fused(
    const float* __restrict__ vs, const float* __restrict__ vt,
    const int* __restrict__ face, const float* __restrict__ rw,
    float* __restrict__ term, double* __restrict__ acc,
    float* __restrict__ out, int nt, int nf, double inv_nf)
{
    const int nthreads = gridDim.x * 256;
    const int tid = blockIdx.x * 256 + threadIdx.x;
    W w = softw(rw);
    if (tid == 0) *acc = 0.0;

    // Phase 1: term[v] for face (v, v+1, v+2); contiguous overlapping loads.
    for (int v = tid; v < nt; v += nthreads) {
        const float* ps = vs + 3 * v;
        const float* pt = vt + 3 * v;
        term[v] = (float)face_term(ldv(ps), ldv(ps + 3), ldv(ps + 6),
                                   ldv(pt), ldv(pt + 3), ldv(pt + 6),
                                   w.shear, w.scale, w.bend);
    }

    cg::this_grid().sync();

    // Phase 2: stream faces as coalesced NT int4 quads, gather term[base].
    const int nq = nf >> 2;
    const iv4* p = reinterpret_cast<const iv4*>(face);
    double a = 0.0;
    for (int q = tid; q < nq; q += nthreads) {
        iv4 A = __builtin_nontemporal_load(p + 3 * q + 0);
        iv4 B = __builtin_nontemporal_load(p + 3 * q + 1);
        iv4 C = __builtin_nontemporal_load(p + 3 * q + 2);
        a += quad_sum(A, B, C, vs, vt, w, term);
    }
    if (tid == 0) {                      // tail (nf % 4 == 0 here)
        for (int j = nq * 4; j < nf; ++j) {
            int x = face[3 * j], y = face[3 * j + 1], z = face[3 * j + 2];
            if (y == x + 1 && z == x + 2) a += (double)term[x];
            else a += face_term(ldv(vs + 3 * x), ldv(vs + 3 * y), ldv(vs + 3 * z),
                                ldv(vt + 3 * x), ldv(vt + 3 * y), ldv(vt + 3 * z),
                                w.shear, w.scale, w.bend);
        }
    }

    __shared__ double sm[4];
    double bs = block_reduce(a, sm);
    if (threadIdx.x == 0) atomicAdd(acc, bs);

    cg::this_grid().sync();
    if (tid == 0) out[0] = (float)((*acc) * inv_nf);
}

// ---------- fallback path: proven R3 three-kernel pipeline ----------
__global__ void __launch_bounds__(256) term_kernel(
    const float* __restrict__ vs, const float* __restrict__ vt,
    const float* __restrict__ rw, float* __restrict__ term, int nt)
{
    int v = blockIdx.x * 256 + threadIdx.x;
    if (v >= nt) return;
    W w = softw(rw);
    const float* ps = vs + 3 * v;
    const float* pt = vt + 3 * v;
    term[v] = (float)face_term(ldv(ps), ldv(ps + 3), ldv(ps + 6),
                               ldv(pt), ldv(pt + 3), ldv(pt + 6),
                               w.shear, w.scale, w.bend);
}

__global__ void __launch_bounds__(256) face_sum(
    const int* __restrict__ face, const float* __restrict__ vs,
    const float* __restrict__ vt, const float* __restrict__ rw,
    const float* __restrict__ term, double* __restrict__ partials, int nf)
{
    int q = blockIdx.x * 256 + threadIdx.x;
    int nq = nf >> 2;
    double a = 0.0;
    W w = softw(rw);
    if (q < nq) {
        const iv4* p = reinterpret_cast<const iv4*>(face) + 3 * q;
        iv4 A = __builtin_nontemporal_load(p + 0);
        iv4 B = __builtin_nontemporal_load(p + 1);
        iv4 C = __builtin_nontemporal_load(p + 2);
        a += quad_sum(A, B, C, vs, vt, w, term);
    }
    if (q == 0) {
        for (int j = nq * 4; j < nf; ++j) {
            int x = face[3 * j], y = face[3 * j + 1], z = face[3 * j + 2];
            if (y == x + 1 && z == x + 2) a += (double)term[x];
            else a += face_term(ldv(vs + 3 * x), ldv(vs + 3 * y), ldv(vs + 3 * z),
                                ldv(vt + 3 * x), ldv(vt + 3 * y), ldv(vt + 3 * z),
                                w.shear, w.scale, w.bend);
        }
    }
    __shared__ double sm[4];
    double bs = block_reduce(a, sm);
    if (threadIdx.x == 0) partials[blockIdx.x] = bs;
}

__global__ void __launch_bounds__(256) deform_finalize(
    const double* __restrict__ partials, int nparts,
    float* __restrict__ out, double inv_nf)
{
    double a = 0.0;
    for (int i = threadIdx.x; i < nparts; i += 256)
        a += partials[i];
    __shared__ double sm[4];
    double bs = block_reduce(a, sm);
    if (threadIdx.x == 0)
        out[0] = (float)(bs * inv_nf);
}

extern "C" void kernel_launch(void* const* d_in, const int* in_sizes, int n_in,
                              void* d_out, int out_size, void* d_ws, size_t ws_size,
                              hipStream_t stream) {
    const float* vs = (const float*)d_in[0];   // (NV,3) f32
    const float* vt = (const float*)d_in[1];   // (NV,3) f32
    const int* face = (const int*)d_in[2];     // (NF,3) i32
    const float* rw = (const float*)d_in[3];   // (3,) f32
    float* out = (float*)d_out;

    int nv = in_sizes[0] / 3;
    int nf = in_sizes[2] / 3;
    int nt = nv - 3;

    float* term = (float*)d_ws;
    size_t term_bytes = ((size_t)nt * 4 + 15) & ~(size_t)15;
    double* acc = (double*)((char*)d_ws + term_bytes);
    double* partials = (double*)((char*)d_ws + term_bytes + 16);
    double inv_nf = 1.0 / (double)nf;

    // Preferred: single cooperative kernel.
    {
        void* args[] = { (void*)&vs, (void*)&vt, (void*)&face, (void*)&rw,
                         (void*)&term, (void*)&acc, (void*)&out,
                         (void*)&nt, (void*)&nf, (void*)&inv_nf };
        hipError_t e = hipLaunchCooperativeKernel(
            reinterpret_cast<void*>(deform_fused),
            dim3(512), dim3(256), args, 0, stream);
        if (e == hipSuccess) return;
        (void)hipGetLastError();  // clear error, fall through to proven path
    }

    // Fallback: R3 three-kernel pipeline (measured 19.6 us).
    int blocks1 = (nt + 255) / 256;
    int nq = nf >> 2;
    int blocks2 = (nq + 255) / 256;
    term_kernel<<<blocks1, 256, 0, stream>>>(vs, vt, rw, term, nt);
    face_sum<<<blocks2, 256, 0, stream>>>(face, vs, vt, rw, term, partials, nf);
    deform_finalize<<<1, 256, 0, stream>>>(partials, blocks2, out, inv_nf);
}

// Round 6
// 40.354 us; speedup vs baseline: 3.3445x; 3.3445x over previous
//
#include <hip/hip_runtime.h>

typedef int iv4 __attribute__((ext_vector_type(4)));

struct W { double shear, scale, bend; };

__device__ __forceinline__ W softw(const float* __restrict__ rw) {
    double r0 = (double)rw[0], r1 = (double)rw[1], r2 = (double)rw[2];
    double mx = fmax(r0, fmax(r1, r2));
    double e0 = exp(r0 - mx), e1 = exp(r1 - mx), e2 = exp(r2 - mx);
    double s = 1.0 / (e0 + e1 + e2);
    W w; w.shear = e0 * s; w.scale = 0.1 * (e1 * s); w.bend = 0.01 * (e2 * s);
    return w;
}

__device__ __forceinline__ float3 ldv(const float* __restrict__ p) {
    return *reinterpret_cast<const float3*>(p);
}

// Per-face loss*area in double.
__device__ __forceinline__ double face_term(
    float3 s0, float3 s1, float3 s2,
    float3 t0, float3 t1, float3 t2,
    double w_shear, double c_scale, double c_bend)
{
    double e1x = (double)s1.x - s0.x, e1y = (double)s1.y - s0.y, e1z = (double)s1.z - s0.z;
    double e2x = (double)s2.x - s0.x, e2y = (double)s2.y - s0.y, e2z = (double)s2.z - s0.z;
    double f1x = e1x - ((double)t1.x - t0.x), f1y = e1y - ((double)t1.y - t0.y), f1z = e1z - ((double)t1.z - t0.z);
    double f2x = e2x - ((double)t2.x - t0.x), f2y = e2y - ((double)t2.y - t0.y), f2z = e2z - ((double)t2.z - t0.z);

    double a = e1x * e1x + e1y * e1y + e1z * e1z;
    double b = e1x * e2x + e1y * e2y + e1z * e2z;
    double c = e2x * e2x + e2y * e2y + e2z * e2z;
    double det = a * c - b * b;

    double crx = e1y * e2z - e1z * e2y;
    double cry = e1z * e2x - e1x * e2z;
    double crz = e1x * e2y - e1y * e2x;
    double crn = crx * crx + cry * cry + crz * crz;
    double area = 0.5 * sqrt(crn);

    double P = crx * f1x + cry * f1y + crz * f1z;
    double Q = crx * f2x + cry * f2y + crz * f2z;
    double norm_loss = (c * P * P - 2.0 * b * P * Q + a * Q * Q) / (det * crn);

    double fe11 = f1x * e1x + f1y * e1y + f1z * e1z;
    double fe12 = f1x * e2x + f1y * e2y + f1z * e2z;
    double fe21 = f2x * e1x + f2y * e1y + f2z * e1z;
    double fe22 = f2x * e2x + f2y * e2y + f2z * e2z;
    double D00 = 2.0 * fe11;
    double D01 = fe12 + fe21;
    double D11 = 2.0 * fe22;

    double idet = 1.0 / det;
    double inv00 = c * idet, inv01 = -b * idet, inv11 = a * idet;

    double stretch = inv00 * D00 + 2.0 * inv01 * D01 + inv11 * D11;
    double offdiag = inv00 * D01 + inv01 * D11 + inv01 * D00 + inv11 * D01;

    double loss = c_bend * norm_loss + c_scale * stretch + w_shear * offdiag;
    return loss * area;
}

__device__ __forceinline__ double quad_sum(iv4 A, iv4 B, iv4 C,
    const float* __restrict__ vs, const float* __restrict__ vt,
    const W& w, const float* __restrict__ term)
{
    int i0[4] = { A[0], A[3], B[2], C[1] };
    int i1[4] = { A[1], B[0], B[3], C[2] };
    int i2[4] = { A[2], B[1], C[0], C[3] };
    double a = 0.0;
    #pragma unroll
    for (int k = 0; k < 4; ++k) {
        if (__builtin_expect(i1[k] == i0[k] + 1 && i2[k] == i0[k] + 2, 1)) {
            a += (double)term[i0[k]];
        } else {   // never taken for this dataset; correctness insurance
            a += face_term(ldv(vs + 3 * i0[k]), ldv(vs + 3 * i1[k]), ldv(vs + 3 * i2[k]),
                           ldv(vt + 3 * i0[k]), ldv(vt + 3 * i1[k]), ldv(vt + 3 * i2[k]),
                           w.shear, w.scale, w.bend);
        }
    }
    return a;
}

__device__ __forceinline__ double block_reduce(double a, double* sm) {
    for (int off = 32; off > 0; off >>= 1)
        a += __shfl_down(a, off);
    int lane = threadIdx.x & 63;
    int wid = threadIdx.x >> 6;
    if (lane == 0) sm[wid] = a;
    __syncthreads();
    return sm[0] + sm[1] + sm[2] + sm[3];
}

// K1: exactly the R3 term kernel (contiguous overlapping loads), plus
// zero-init of acc/cnt by block 0 (stream-ordered before K2; poison-safe).
__global__ void __launch_bounds__(256) term_kernel(
    const float* __restrict__ vs, const float* __restrict__ vt,
    const float* __restrict__ rw, float* __restrict__ term,
    double* __restrict__ acc, unsigned* __restrict__ cnt, int nt)
{
    int v = blockIdx.x * 256 + threadIdx.x;
    if (blockIdx.x == 0 && threadIdx.x == 0) { *acc = 0.0; *cnt = 0u; }
    if (v >= nt) return;
    W w = softw(rw);
    const float* ps = vs + 3 * v;
    const float* pt = vt + 3 * v;
    term[v] = (float)face_term(ldv(ps), ldv(ps + 3), ldv(ps + 6),
                               ldv(pt), ldv(pt + 3), ldv(pt + 6),
                               w.shear, w.scale, w.bend);
}

// K2: exactly the R3 face_sum (1 quad/thread, full grid), with the finalize
// folded in: one f64 atomicAdd per block + last-block-out writes d_out.
__global__ void __launch_bounds__(256) face_sum(
    const int* __restrict__ face, const float* __restrict__ vs,
    const float* __restrict__ vt, const float* __restrict__ rw,
    const float* __restrict__ term,
    double* __restrict__ acc, unsigned* __restrict__ cnt,
    float* __restrict__ out, int nf, int nblocks, double inv_nf)
{
    int q = blockIdx.x * 256 + threadIdx.x;
    int nq = nf >> 2;
    double a = 0.0;
    W w = softw(rw);
    if (q < nq) {
        const iv4* p = reinterpret_cast<const iv4*>(face) + 3 * q;
        iv4 A = __builtin_nontemporal_load(p + 0);
        iv4 B = __builtin_nontemporal_load(p + 1);
        iv4 C = __builtin_nontemporal_load(p + 2);
        a += quad_sum(A, B, C, vs, vt, w, term);
    }
    if (q == 0) {                        // scalar tail (nf % 4 == 0 here)
        for (int j = nq * 4; j < nf; ++j) {
            int x = face[3 * j], y = face[3 * j + 1], z = face[3 * j + 2];
            if (y == x + 1 && z == x + 2) a += (double)term[x];
            else a += face_term(ldv(vs + 3 * x), ldv(vs + 3 * y), ldv(vs + 3 * z),
                                ldv(vt + 3 * x), ldv(vt + 3 * y), ldv(vt + 3 * z),
                                w.shear, w.scale, w.bend);
        }
    }

    __shared__ double sm[4];
    double bs = block_reduce(a, sm);

    if (threadIdx.x == 0) {
        atomicAdd(acc, bs);
        __threadfence();
        unsigned done = atomicAdd(cnt, 1u);
        if (done == (unsigned)(nblocks - 1)) {   // last block out finalizes
            __threadfence();
            double total = atomicAdd(acc, 0.0);  // device-scope read
            out[0] = (float)(total * inv_nf);
        }
    }
}

extern "C" void kernel_launch(void* const* d_in, const int* in_sizes, int n_in,
                              void* d_out, int out_size, void* d_ws, size_t ws_size,
                              hipStream_t stream) {
    const float* vs = (const float*)d_in[0];   // (NV,3) f32
    const float* vt = (const float*)d_in[1];   // (NV,3) f32
    const int* face = (const int*)d_in[2];     // (NF,3) i32
    const float* rw = (const float*)d_in[3];   // (3,) f32
    float* out = (float*)d_out;

    int nv = in_sizes[0] / 3;
    int nf = in_sizes[2] / 3;
    int nt = nv - 3;

    float* term = (float*)d_ws;
    size_t term_bytes = ((size_t)nt * 4 + 15) & ~(size_t)15;
    double* acc = (double*)((char*)d_ws + term_bytes);
    unsigned* cnt = (unsigned*)((char*)d_ws + term_bytes + 8);
    double inv_nf = 1.0 / (double)nf;

    int blocks1 = (nt + 255) / 256;
    int nq = nf >> 2;
    int blocks2 = (nq + 255) / 256;

    term_kernel<<<blocks1, 256, 0, stream>>>(vs, vt, rw, term, acc, cnt, nt);
    face_sum<<<blocks2, 256, 0, stream>>>(face, vs, vt, rw, term, acc, cnt,
                                          out, nf, blocks2, inv_nf);
}

// Round 7
// 28.237 us; speedup vs baseline: 4.7797x; 1.4291x over previous
//
#include <hip/hip_runtime.h>

typedef int iv4 __attribute__((ext_vector_type(4)));

struct W { double shear, scale, bend; };

__device__ __forceinline__ W softw(const float* __restrict__ rw) {
    double r0 = (double)rw[0], r1 = (double)rw[1], r2 = (double)rw[2];
    double mx = fmax(r0, fmax(r1, r2));
    double e0 = exp(r0 - mx), e1 = exp(r1 - mx), e2 = exp(r2 - mx);
    double s = 1.0 / (e0 + e1 + e2);
    W w; w.shear = e0 * s; w.scale = 0.1 * (e1 * s); w.bend = 0.01 * (e2 * s);
    return w;
}

__device__ __forceinline__ float3 ldv(const float* __restrict__ p) {
    return *reinterpret_cast<const float3*>(p);
}

// Per-face loss*area in double.
__device__ __forceinline__ double face_term(
    float3 s0, float3 s1, float3 s2,
    float3 t0, float3 t1, float3 t2,
    double w_shear, double c_scale, double c_bend)
{
    double e1x = (double)s1.x - s0.x, e1y = (double)s1.y - s0.y, e1z = (double)s1.z - s0.z;
    double e2x = (double)s2.x - s0.x, e2y = (double)s2.y - s0.y, e2z = (double)s2.z - s0.z;
    double f1x = e1x - ((double)t1.x - t0.x), f1y = e1y - ((double)t1.y - t0.y), f1z = e1z - ((double)t1.z - t0.z);
    double f2x = e2x - ((double)t2.x - t0.x), f2y = e2y - ((double)t2.y - t0.y), f2z = e2z - ((double)t2.z - t0.z);

    double a = e1x * e1x + e1y * e1y + e1z * e1z;
    double b = e1x * e2x + e1y * e2y + e1z * e2z;
    double c = e2x * e2x + e2y * e2y + e2z * e2z;
    double det = a * c - b * b;

    double crx = e1y * e2z - e1z * e2y;
    double cry = e1z * e2x - e1x * e2z;
    double crz = e1x * e2y - e1y * e2x;
    double crn = crx * crx + cry * cry + crz * crz;
    double area = 0.5 * sqrt(crn);

    double P = crx * f1x + cry * f1y + crz * f1z;
    double Q = crx * f2x + cry * f2y + crz * f2z;
    double norm_loss = (c * P * P - 2.0 * b * P * Q + a * Q * Q) / (det * crn);

    double fe11 = f1x * e1x + f1y * e1y + f1z * e1z;
    double fe12 = f1x * e2x + f1y * e2y + f1z * e2z;
    double fe21 = f2x * e1x + f2y * e1y + f2z * e1z;
    double fe22 = f2x * e2x + f2y * e2y + f2z * e2z;
    double D00 = 2.0 * fe11;
    double D01 = fe12 + fe21;
    double D11 = 2.0 * fe22;

    double idet = 1.0 / det;
    double inv00 = c * idet, inv01 = -b * idet, inv11 = a * idet;

    double stretch = inv00 * D00 + 2.0 * inv01 * D01 + inv11 * D11;
    double offdiag = inv00 * D01 + inv01 * D11 + inv01 * D00 + inv11 * D01;

    double loss = c_bend * norm_loss + c_scale * stretch + w_shear * offdiag;
    return loss * area;
}

__device__ __forceinline__ double quad_sum(iv4 A, iv4 B, iv4 C,
    const float* __restrict__ vs, const float* __restrict__ vt,
    const W& w, const float* __restrict__ term)
{
    int i0[4] = { A[0], A[3], B[2], C[1] };
    int i1[4] = { A[1], B[0], B[3], C[2] };
    int i2[4] = { A[2], B[1], C[0], C[3] };
    double a = 0.0;
    #pragma unroll
    for (int k = 0; k < 4; ++k) {
        if (__builtin_expect(i1[k] == i0[k] + 1 && i2[k] == i0[k] + 2, 1)) {
            a += (double)term[i0[k]];
        } else {   // never taken for this dataset; correctness insurance
            a += face_term(ldv(vs + 3 * i0[k]), ldv(vs + 3 * i1[k]), ldv(vs + 3 * i2[k]),
                           ldv(vt + 3 * i0[k]), ldv(vt + 3 * i1[k]), ldv(vt + 3 * i2[k]),
                           w.shear, w.scale, w.bend);
        }
    }
    return a;
}

__device__ __forceinline__ double block_reduce(double a, double* sm) {
    for (int off = 32; off > 0; off >>= 1)
        a += __shfl_down(a, off);
    int lane = threadIdx.x & 63;
    int wid = threadIdx.x >> 6;
    if (lane == 0) sm[wid] = a;
    __syncthreads();
    return sm[0] + sm[1] + sm[2] + sm[3];
}

// K1: exact R3 term kernel (contiguous overlapping loads). Block 0 also
// zeroes out[0] (stream-ordered before K2 -> poison-safe, re-done each call).
__global__ void __launch_bounds__(256) term_kernel(
    const float* __restrict__ vs, const float* __restrict__ vt,
    const float* __restrict__ rw, float* __restrict__ term,
    float* __restrict__ out, int nt)
{
    if (blockIdx.x == 0 && threadIdx.x == 0) out[0] = 0.0f;
    int v = blockIdx.x * 256 + threadIdx.x;
    if (v >= nt) return;
    W w = softw(rw);
    const float* ps = vs + 3 * v;
    const float* pt = vt + 3 * v;
    term[v] = (float)face_term(ldv(ps), ldv(ps + 3), ldv(ps + 6),
                               ldv(pt), ldv(pt + 3), ldv(pt + 6),
                               w.shear, w.scale, w.bend);
}

// K2: exact R3 face_sum, but finalize is a single RELAXED f32 atomicAdd to
// d_out per block (no fence, no counter, no third kernel).
__global__ void __launch_bounds__(256) face_sum(
    const int* __restrict__ face, const float* __restrict__ vs,
    const float* __restrict__ vt, const float* __restrict__ rw,
    const float* __restrict__ term, float* __restrict__ out,
    int nf, double inv_nf)
{
    int q = blockIdx.x * 256 + threadIdx.x;
    int nq = nf >> 2;
    double a = 0.0;
    W w = softw(rw);
    if (q < nq) {
        const iv4* p = reinterpret_cast<const iv4*>(face) + 3 * q;
        iv4 A = __builtin_nontemporal_load(p + 0);
        iv4 B = __builtin_nontemporal_load(p + 1);
        iv4 C = __builtin_nontemporal_load(p + 2);
        a += quad_sum(A, B, C, vs, vt, w, term);
    }
    if (q == 0) {                        // scalar tail (nf % 4 == 0 here)
        for (int j = nq * 4; j < nf; ++j) {
            int x = face[3 * j], y = face[3 * j + 1], z = face[3 * j + 2];
            if (y == x + 1 && z == x + 2) a += (double)term[x];
            else a += face_term(ldv(vs + 3 * x), ldv(vs + 3 * y), ldv(vs + 3 * z),
                                ldv(vt + 3 * x), ldv(vt + 3 * y), ldv(vt + 3 * z),
                                w.shear, w.scale, w.bend);
        }
    }

    __shared__ double sm[4];
    double bs = block_reduce(a, sm);
    if (threadIdx.x == 0)
        atomicAdd(out, (float)(bs * inv_nf));   // relaxed, fence-free
}

extern "C" void kernel_launch(void* const* d_in, const int* in_sizes, int n_in,
                              void* d_out, int out_size, void* d_ws, size_t ws_size,
                              hipStream_t stream) {
    const float* vs = (const float*)d_in[0];   // (NV,3) f32
    const float* vt = (const float*)d_in[1];   // (NV,3) f32
    const int* face = (const int*)d_in[2];     // (NF,3) i32
    const float* rw = (const float*)d_in[3];   // (3,) f32
    float* out = (float*)d_out;

    int nv = in_sizes[0] / 3;
    int nf = in_sizes[2] / 3;
    int nt = nv - 3;

    float* term = (float*)d_ws;
    double inv_nf = 1.0 / (double)nf;

    int blocks1 = (nt + 255) / 256;
    int nq = nf >> 2;
    int blocks2 = (nq + 255) / 256;

    term_kernel<<<blocks1, 256, 0, stream>>>(vs, vt, rw, term, out, nt);
    face_sum<<<blocks2, 256, 0, stream>>>(face, vs, vt, rw, term, out, nf, inv_nf);
}

// Round 8
// 19.838 us; speedup vs baseline: 6.8033x; 1.4234x over previous
//
#include <hip/hip_runtime.h>

typedef int iv4 __attribute__((ext_vector_type(4)));

// ---------- f32 softmax weights (error ~1e-7 rel, budget is 2%) ----------
struct Wf { float shear, scale, bend; };

__device__ __forceinline__ Wf softwf(const float* __restrict__ rw) {
    float r0 = rw[0], r1 = rw[1], r2 = rw[2];
    float mx = fmaxf(r0, fmaxf(r1, r2));
    float e0 = expf(r0 - mx), e1 = expf(r1 - mx), e2 = expf(r2 - mx);
    float s = 1.0f / (e0 + e1 + e2);
    Wf w; w.shear = e0 * s; w.scale = 0.1f * (e1 * s); w.bend = 0.01f * (e2 * s);
    return w;
}

__device__ __forceinline__ float3 ldv(const float* __restrict__ p) {
    return *reinterpret_cast<const float3*>(p);
}

// ---------- full f64 per-face term (fallback for ill-conditioned faces) ----------
__device__ __noinline__ double face_term_f64(
    float3 s0, float3 s1, float3 s2,
    float3 t0, float3 t1, float3 t2,
    double w_shear, double c_scale, double c_bend)
{
    double e1x = (double)s1.x - s0.x, e1y = (double)s1.y - s0.y, e1z = (double)s1.z - s0.z;
    double e2x = (double)s2.x - s0.x, e2y = (double)s2.y - s0.y, e2z = (double)s2.z - s0.z;
    double f1x = e1x - ((double)t1.x - t0.x), f1y = e1y - ((double)t1.y - t0.y), f1z = e1z - ((double)t1.z - t0.z);
    double f2x = e2x - ((double)t2.x - t0.x), f2y = e2y - ((double)t2.y - t0.y), f2z = e2z - ((double)t2.z - t0.z);

    double a = e1x * e1x + e1y * e1y + e1z * e1z;
    double b = e1x * e2x + e1y * e2y + e1z * e2z;
    double c = e2x * e2x + e2y * e2y + e2z * e2z;
    double det = a * c - b * b;

    double crx = e1y * e2z - e1z * e2y;
    double cry = e1z * e2x - e1x * e2z;
    double crz = e1x * e2y - e1y * e2x;
    double crn = crx * crx + cry * cry + crz * crz;
    double area = 0.5 * sqrt(crn);

    double P = crx * f1x + cry * f1y + crz * f1z;
    double Q = crx * f2x + cry * f2y + crz * f2z;
    double norm_loss = (c * P * P - 2.0 * b * P * Q + a * Q * Q) / (det * crn);

    double fe11 = f1x * e1x + f1y * e1y + f1z * e1z;
    double fe12 = f1x * e2x + f1y * e2y + f1z * e2z;
    double fe21 = f2x * e1x + f2y * e1y + f2z * e1z;
    double fe22 = f2x * e2x + f2y * e2y + f2z * e2z;
    double D00 = 2.0 * fe11;
    double D01 = fe12 + fe21;
    double D11 = 2.0 * fe22;

    double idet = 1.0 / det;
    double inv00 = c * idet, inv01 = -b * idet, inv11 = a * idet;

    double stretch = inv00 * D00 + 2.0 * inv01 * D01 + inv11 * D11;
    double offdiag = inv00 * D01 + inv01 * D11 + inv01 * D00 + inv11 * D01;

    double loss = c_bend * norm_loss + c_scale * stretch + w_shear * offdiag;
    return loss * area;
}

// ---------- mixed-precision per-face term: f32 fast path, f64 redo if det
// is cancellation-dominated (det <= 1e-3 * a*c; ~5e-4 of faces) ----------
__device__ __forceinline__ float face_term_mixed(
    float3 s0, float3 s1, float3 s2,
    float3 t0, float3 t1, float3 t2, Wf w)
{
    float e1x = s1.x - s0.x, e1y = s1.y - s0.y, e1z = s1.z - s0.z;
    float e2x = s2.x - s0.x, e2y = s2.y - s0.y, e2z = s2.z - s0.z;
    float f1x = e1x - (t1.x - t0.x), f1y = e1y - (t1.y - t0.y), f1z = e1z - (t1.z - t0.z);
    float f2x = e2x - (t2.x - t0.x), f2y = e2y - (t2.y - t0.y), f2z = e2z - (t2.z - t0.z);

    float a = e1x * e1x + e1y * e1y + e1z * e1z;
    float b = e1x * e2x + e1y * e2y + e1z * e2z;
    float c = e2x * e2x + e2y * e2y + e2z * e2z;
    float det = a * c - b * b;

    if (__builtin_expect(!(det > 1e-3f * a * c), 0)) {
        // ill-conditioned: full f64 redo (rare; ~3% of waves diverge here)
        return (float)face_term_f64(s0, s1, s2, t0, t1, t2,
                                    (double)w.shear, (double)w.scale, (double)w.bend);
    }

    float crx = e1y * e2z - e1z * e2y;
    float cry = e1z * e2x - e1x * e2z;
    float crz = e1x * e2y - e1y * e2x;
    float crn = crx * crx + cry * cry + crz * crz;
    float area = 0.5f * sqrtf(crn);

    float P = crx * f1x + cry * f1y + crz * f1z;
    float Q = crx * f2x + cry * f2y + crz * f2z;
    float norm_loss = (c * P * P - 2.0f * b * P * Q + a * Q * Q) / (det * crn);

    float fe11 = f1x * e1x + f1y * e1y + f1z * e1z;
    float fe12 = f1x * e2x + f1y * e2y + f1z * e2z;
    float fe21 = f2x * e1x + f2y * e1y + f2z * e1z;
    float fe22 = f2x * e2x + f2y * e2y + f2z * e2z;
    float D00 = 2.0f * fe11;
    float D01 = fe12 + fe21;
    float D11 = 2.0f * fe22;

    float idet = 1.0f / det;
    float inv00 = c * idet, inv01 = -b * idet, inv11 = a * idet;

    float stretch = inv00 * D00 + 2.0f * inv01 * D01 + inv11 * D11;
    float offdiag = inv00 * D01 + inv01 * D11 + inv01 * D00 + inv11 * D01;

    float loss = w.bend * norm_loss + w.scale * stretch + w.shear * offdiag;
    return loss * area;
}

__device__ __forceinline__ double block_reduce(double a, double* sm) {
    for (int off = 32; off > 0; off >>= 1)
        a += __shfl_down(a, off);
    int lane = threadIdx.x & 63;
    int wid = threadIdx.x >> 6;
    if (lane == 0) sm[wid] = a;
    __syncthreads();
    return sm[0] + sm[1] + sm[2] + sm[3];
}

// K1: term[v] for face (v, v+1, v+2); contiguous overlapping loads, f32 math.
__global__ void __launch_bounds__(256) term_kernel(
    const float* __restrict__ vs, const float* __restrict__ vt,
    const float* __restrict__ rw, float* __restrict__ term, int nt)
{
    int v = blockIdx.x * 256 + threadIdx.x;
    if (v >= nt) return;
    Wf w = softwf(rw);
    const float* ps = vs + 3 * v;
    const float* pt = vt + 3 * v;
    term[v] = face_term_mixed(ldv(ps), ldv(ps + 3), ldv(ps + 6),
                              ldv(pt), ldv(pt + 3), ldv(pt + 6), w);
}

__device__ __forceinline__ double quad_sum(iv4 A, iv4 B, iv4 C,
    const float* __restrict__ vs, const float* __restrict__ vt,
    const float* __restrict__ rw, const float* __restrict__ term)
{
    int i0[4] = { A[0], A[3], B[2], C[1] };
    int i1[4] = { A[1], B[0], B[3], C[2] };
    int i2[4] = { A[2], B[1], C[0], C[3] };
    double a = 0.0;
    #pragma unroll
    for (int k = 0; k < 4; ++k) {
        if (__builtin_expect(i1[k] == i0[k] + 1 && i2[k] == i0[k] + 2, 1)) {
            a += (double)term[i0[k]];
        } else {
            // never taken for this dataset; correctness insurance.
            // softmax computed HERE (cold path) so the hot path has no exp.
            Wf w = softwf(rw);
            a += (double)face_term_mixed(
                    ldv(vs + 3 * i0[k]), ldv(vs + 3 * i1[k]), ldv(vs + 3 * i2[k]),
                    ldv(vt + 3 * i0[k]), ldv(vt + 3 * i1[k]), ldv(vt + 3 * i2[k]), w);
        }
    }
    return a;
}

// K2: stream faces as coalesced NT int4, gather term[base], write partials.
__global__ void __launch_bounds__(256) face_sum(
    const int* __restrict__ face, const float* __restrict__ vs,
    const float* __restrict__ vt, const float* __restrict__ rw,
    const float* __restrict__ term, double* __restrict__ partials, int nf)
{
    int q = blockIdx.x * 256 + threadIdx.x;
    int nq = nf >> 2;
    double a = 0.0;
    if (q < nq) {
        const iv4* p = reinterpret_cast<const iv4*>(face) + 3 * q;
        iv4 A = __builtin_nontemporal_load(p + 0);
        iv4 B = __builtin_nontemporal_load(p + 1);
        iv4 C = __builtin_nontemporal_load(p + 2);
        a += quad_sum(A, B, C, vs, vt, rw, term);
    }
    if (q == 0) {                        // scalar tail (nf % 4 == 0 here)
        for (int j = nq * 4; j < nf; ++j) {
            int x = face[3 * j], y = face[3 * j + 1], z = face[3 * j + 2];
            if (y == x + 1 && z == x + 2) a += (double)term[x];
            else {
                Wf w = softwf(rw);
                a += (double)face_term_mixed(
                        ldv(vs + 3 * x), ldv(vs + 3 * y), ldv(vs + 3 * z),
                        ldv(vt + 3 * x), ldv(vt + 3 * y), ldv(vt + 3 * z), w);
            }
        }
    }
    __shared__ double sm[4];
    double bs = block_reduce(a, sm);
    if (threadIdx.x == 0) partials[blockIdx.x] = bs;
}

__global__ void __launch_bounds__(256) deform_finalize(
    const double* __restrict__ partials, int nparts,
    float* __restrict__ out, double inv_nf)
{
    double a = 0.0;
    for (int i = threadIdx.x; i < nparts; i += 256)
        a += partials[i];
    __shared__ double sm[4];
    double bs = block_reduce(a, sm);
    if (threadIdx.x == 0)
        out[0] = (float)(bs * inv_nf);
}

extern "C" void kernel_launch(void* const* d_in, const int* in_sizes, int n_in,
                              void* d_out, int out_size, void* d_ws, size_t ws_size,
                              hipStream_t stream) {
    const float* vs = (const float*)d_in[0];   // (NV,3) f32
    const float* vt = (const float*)d_in[1];   // (NV,3) f32
    const int* face = (const int*)d_in[2];     // (NF,3) i32
    const float* rw = (const float*)d_in[3];   // (3,) f32
    float* out = (float*)d_out;

    int nv = in_sizes[0] / 3;
    int nf = in_sizes[2] / 3;
    int nt = nv - 3;

    float* term = (float*)d_ws;
    size_t term_bytes = ((size_t)nt * 4 + 15) & ~(size_t)15;
    double* partials = (double*)((char*)d_ws + term_bytes);
    double inv_nf = 1.0 / (double)nf;

    int blocks1 = (nt + 255) / 256;
    int nq = nf >> 2;
    int blocks2 = (nq + 255) / 256;

    term_kernel<<<blocks1, 256, 0, stream>>>(vs, vt, rw, term, nt);
    face_sum<<<blocks2, 256, 0, stream>>>(face, vs, vt, rw, term, partials, nf);
    deform_finalize<<<1, 256, 0, stream>>>(partials, blocks2, out, inv_nf);
}